// Round 2
// baseline (5819.471 us; speedup 1.0000x reference)
//
#include <hip/hip_runtime.h>

using bf16x8 = __attribute__((ext_vector_type(8))) short;
using f32x4  = __attribute__((ext_vector_type(4))) float;

__device__ inline float bf2f(unsigned short h){
  union { unsigned int u; float f; } v; v.u = ((unsigned int)h) << 16; return v.f;
}
__device__ inline unsigned short f2b(float x){
  union { float f; unsigned int u; } v; v.f = x;
  unsigned int r = (v.u + 0x7FFFu + ((v.u >> 16) & 1u)) >> 16;
  return (unsigned short)r;
}
__device__ inline float blo(unsigned int u){ union{unsigned int v; float f;} t; t.v = u << 16; return t.f; }
__device__ inline float bhi(unsigned int u){ union{unsigned int v; float f;} t; t.v = u & 0xffff0000u; return t.f; }

// ---------------------------------------------------------------------------
// fp32 -> bf16 bulk convert (n multiple of 4)
__global__ void conv_k(const float* __restrict__ s, unsigned short* __restrict__ d, int n){
  int i = (blockIdx.x * 256 + threadIdx.x) * 4;
  if (i >= n) return;
  float4 v = *(const float4*)(s + i);
  unsigned int p0 = (unsigned int)f2b(v.x) | ((unsigned int)f2b(v.y) << 16);
  unsigned int p1 = (unsigned int)f2b(v.z) | ((unsigned int)f2b(v.w) << 16);
  *(uint2*)(d + i) = make_uint2(p0, p1);
}

// W_dec (256x512 f32) -> WdecT (512x256 bf16, k-major). Coalesced writes.
__global__ void wdect_k(const float* __restrict__ Wd, unsigned short* __restrict__ o){
  int idx = blockIdx.x * 256 + threadIdx.x;   // idx = k*256 + a
  int k = idx >> 8, a = idx & 255;
  o[idx] = f2b(Wd[a * 512 + k]);
}

// Reorder an f32 weight slice (row-major, leading dim ld, col offset koff,
// 1536 rows x 512 cols) into MFMA-16x16x32 B-fragment order, bf16:
// dst[((nt*16 + kit)*64 + lane)*8 + j] = W[nt*16 + (lane&15)][koff + kit*32 + (lane>>4)*8 + j]
// so a wave's B-frag for (n-tile nt, k-step kit) is one contiguous 1 KB chunk.
__global__ void wfrag_k(const float* __restrict__ src, int ld, int koff,
                        unsigned short* __restrict__ dst){
  int d = blockIdx.x * 256 + threadIdx.x;      // 1536*512 elements
  int j = d & 7, lane = (d >> 3) & 63, kit = (d >> 9) & 15, nt = d >> 13;
  int n = nt * 16 + (lane & 15);
  int k = kit * 32 + ((lane >> 4) << 3) + j;
  dst[d] = f2b(src[(long)n * ld + koff + k]);
}

// embedding gather (pad_idx=2 -> 0), rows m = t*64+b, bf16 out
__global__ void embed_k(const int* __restrict__ tgt, const float* __restrict__ emb,
                        unsigned short* __restrict__ out, int n){
  int idx = blockIdx.x * 256 + threadIdx.x;
  if (idx >= n) return;
  int d = idx & 511, m = idx >> 9, t = m >> 6, b = m & 63;
  int tok = tgt[b * 32 + t];
  float v = (tok == 2) ? 0.f : emb[(long)tok * 512 + d];
  out[idx] = f2b(v);
}

// ---------------------------------------------------------------------------
// Generic bf16 MFMA GEMM: C[m][n] = sum_k A[m][k]*B[n][k] (+bias[n])
#define EPI_PLAIN 0
#define EPI_TANH  1
#define EPI_OUT   2
#define EPI_B16   3

template<int EPI, bool AF32>
__global__ __launch_bounds__(256)
void gemm_bt(const void* __restrict__ Av, int lda,
             const unsigned short* __restrict__ Bp, int ldb,
             const float* __restrict__ bias,
             float* __restrict__ Cf, unsigned short* __restrict__ Cb, int ldc,
             int K,
             int n_split, const void* __restrict__ A2v,
             const unsigned short* __restrict__ B2p, int lda2, int ldb2)
{
  __shared__ __align__(16) unsigned short As[64][40];
  __shared__ __align__(16) unsigned short Bs[256][40];

  int m0 = blockIdx.x * 64;
  int n0 = blockIdx.y * 256;
  const void* Ap = Av; const unsigned short* Bq = Bp;
  int la = lda, lb = ldb, nB = n0;
  if (n_split > 0 && n0 >= n_split){ Ap = A2v; Bq = B2p; la = lda2; lb = ldb2; nB = n0 - n_split; }

  int tid  = threadIdx.x;
  int wave = tid >> 6, lane = tid & 63, quad = lane >> 4, lrow = lane & 15;

  f32x4 acc[4][4];
#pragma unroll
  for (int i = 0; i < 4; ++i)
#pragma unroll
    for (int j = 0; j < 4; ++j)
#pragma unroll
      for (int r = 0; r < 4; ++r) acc[i][j][r] = 0.f;

  int ar = tid >> 2, ac = (tid & 3) * 8;

  for (int k0 = 0; k0 < K; k0 += 32){
    if (AF32){
      const float* A32 = (const float*)Ap;
      const float4* src = (const float4*)(A32 + (long)(m0 + ar) * la + k0 + ac);
      float4 x0 = src[0], x1 = src[1];
      unsigned int p0 = (unsigned int)f2b(x0.x) | ((unsigned int)f2b(x0.y) << 16);
      unsigned int p1 = (unsigned int)f2b(x0.z) | ((unsigned int)f2b(x0.w) << 16);
      unsigned int p2 = (unsigned int)f2b(x1.x) | ((unsigned int)f2b(x1.y) << 16);
      unsigned int p3 = (unsigned int)f2b(x1.z) | ((unsigned int)f2b(x1.w) << 16);
      *(uint4*)&As[ar][ac] = make_uint4(p0, p1, p2, p3);
    } else {
      const unsigned short* A16 = (const unsigned short*)Ap;
      *(uint4*)&As[ar][ac] = *(const uint4*)(A16 + (long)(m0 + ar) * la + k0 + ac);
    }
#pragma unroll
    for (int c = 0; c < 4; ++c){
      int id = tid + c * 256; int br = id >> 2, bc = (id & 3) * 8;
      *(uint4*)&Bs[br][bc] = *(const uint4*)(Bq + (long)(nB + br) * lb + k0 + bc);
    }
    __syncthreads();

    bf16x8 af[4], bfr[4];
#pragma unroll
    for (int mf = 0; mf < 4; ++mf) af[mf]  = *(const bf16x8*)&As[mf * 16 + lrow][quad * 8];
#pragma unroll
    for (int nf = 0; nf < 4; ++nf) bfr[nf] = *(const bf16x8*)&Bs[wave * 64 + nf * 16 + lrow][quad * 8];
#pragma unroll
    for (int mf = 0; mf < 4; ++mf)
#pragma unroll
      for (int nf = 0; nf < 4; ++nf)
        acc[mf][nf] = __builtin_amdgcn_mfma_f32_16x16x32_bf16(af[mf], bfr[nf], acc[mf][nf], 0, 0, 0);
    __syncthreads();
  }

#pragma unroll
  for (int mf = 0; mf < 4; ++mf){
#pragma unroll
    for (int nf = 0; nf < 4; ++nf){
#pragma unroll
      for (int r = 0; r < 4; ++r){
        int m = m0 + mf * 16 + quad * 4 + r;
        int n = n0 + wave * 64 + nf * 16 + lrow;
        float v = acc[mf][nf][r];
        if (bias) v += bias[n];
        if (EPI == EPI_TANH){
          v = tanhf(v);
          Cf[(long)m * ldc + n] = v;
          Cb[(long)m * ldc + n] = f2b(v);
        } else if (EPI == EPI_OUT){
          Cf[(long)(m & 63) * (31 * 32000) + (long)(m >> 6) * 32000 + n] = v;
        } else if (EPI == EPI_B16){
          Cb[(long)m * ldc + n] = f2b(v);
        } else {
          Cf[(long)m * ldc + n] = v;
        }
      }
    }
  }
}

// ---------------------------------------------------------------------------
// Persistent per-batch decoder loop: ONE kernel runs all 32 steps.
// 64 blocks (1/batch) x 512 threads. The per-batch recurrence is fully
// independent across b, so there are no grid syncs and no launches.
// Weights for the per-step giq GEMV (M=1) are consumed via MFMA with
// fragment-order pre-reordered layout -> every load is a coalesced 16 B/lane.
// ep (196x256 bf16) stays staged in LDS across all steps.
__global__ __launch_bounds__(512)
void loop_k(const uint4* __restrict__ ep4,          // enc_proj bf16 [(b*196+s)*256+a]
            const unsigned int* __restrict__ eo2,   // enc_out bf16 pairs
            const float* __restrict__ W_score,
            const float* __restrict__ b_dec,
            const float* __restrict__ b_hh,
            const float* __restrict__ gi_emb,
            const float* __restrict__ h0_all,       // (64,512) f32, t=0 hidden
            unsigned short* __restrict__ h_b16,     // (32,64,512) bf16 out
            const uint2* __restrict__ WdecT4,       // bf16 [k][a] k-major
            const unsigned short* __restrict__ Wihf,// frag-order Wih[:,512:]
            const unsigned short* __restrict__ Whhf)// frag-order Whh
{
  __shared__ __align__(16) uint4 ep_s4[6272];       // 98 KB, swizzled
  __shared__ float sh_h[512];
  __shared__ unsigned short sh_hb[512];
  __shared__ unsigned short sh_cb[512];
  __shared__ float2 dpw[256];
  __shared__ float spart[2048];
  __shared__ float sw[256];
  __shared__ float wred[16];
  __shared__ float giq_lds[3072];

  int b = blockIdx.x, tid = threadIdx.x;
  int lane = tid & 63, wv = tid >> 6, quad = lane >> 4, lrow = lane & 15;

  // loop-invariant preloads
  float wsc  = (tid < 256) ? W_score[tid] : 0.f;
  float bdec = (tid < 256) ? b_dec[tid] : 0.f;
  float bhh0 = b_hh[tid], bhh1 = b_hh[512 + tid], bhh2 = b_hh[1024 + tid];

  // stage enc_proj[b] once (chunk-XOR swizzle: conflict-free ds_read_b128)
  {
    const uint4* src = ep4 + (long)b * 6272;
    for (int c = tid; c < 6272; c += 512){
      int r = c >> 5, col = c & 31;
      ep_s4[(r << 5) | (col ^ (r & 7))] = src[c];
    }
  }

  float h_prev = 0.f;

  for (int t = 0; t <= 31; ++t){
    // ---- GRU gates -> h_t (t=0: read h0) ----
    float hv;
    if (t > 0){
      int j = tid;
      long ge = ((long)(t - 1) * 64 + b) * 1536;
      float gir = gi_emb[ge + j]        + giq_lds[j];
      float giz = gi_emb[ge + 512 + j]  + giq_lds[512 + j];
      float gin = gi_emb[ge + 1024 + j] + giq_lds[1024 + j];
      float ghr = giq_lds[1536 + j] + bhh0;
      float ghz = giq_lds[2048 + j] + bhh1;
      float ghn = giq_lds[2560 + j] + bhh2;
      float rr = 1.f / (1.f + __expf(-(gir + ghr)));
      float zz = 1.f / (1.f + __expf(-(giz + ghz)));
      float nn = tanhf(gin + rr * ghn);
      hv = (1.f - zz) * nn + zz * h_prev;
      h_b16[((long)t * 64 + b) * 512 + j] = f2b(hv);
    } else {
      hv = h0_all[(long)b * 512 + tid];
    }
    h_prev = hv;
    if (t == 31) break;                 // uniform: h_31 written, done

    sh_h[tid] = hv;
    sh_hb[tid] = f2b(hv);
    __syncthreads();

    // ---- dec_proj[a] = h . W_dec[a,:] + b_dec[a] (k-major GEMV) ----
    {
      int a4 = tid & 63, kg = tid >> 6;
      const uint2* wp = WdecT4 + ((kg << 12) | a4);
      const float* hp = &sh_h[kg << 6];
      float ac0 = 0.f, ac1 = 0.f, ac2 = 0.f, ac3 = 0.f;
#pragma unroll 16
      for (int kk = 0; kk < 64; ++kk){
        uint2 wq = wp[kk << 6];
        float hk = hp[kk];
        ac0 += hk * blo(wq.x); ac1 += hk * bhi(wq.x);
        ac2 += hk * blo(wq.y); ac3 += hk * bhi(wq.y);
      }
      *(float4*)&spart[(kg << 8) | (a4 << 2)] = make_float4(ac0, ac1, ac2, ac3);
    }
    __syncthreads();
    if (tid < 256){
      float dp = bdec;
#pragma unroll
      for (int kg = 0; kg < 8; ++kg) dp += spart[(kg << 8) | tid];
      dpw[tid] = make_float2(dp, wsc);
    }
    __syncthreads();

    // ---- scores[s] = sum_a wsc[a]*tanh(ep[s][a]+dp[a]) ----
    {
      int s = tid & 255, half = tid >> 8;
      float acc = 0.f;
      if (s < 196){
        int rb = s << 5, sx = s & 7;
#pragma unroll 4
        for (int j = 0; j < 16; ++j){
          uint4 v = ep_s4[rb | (((half << 4) | j) ^ sx)];
          int aj = (half << 7) | (j << 3);
#define SCP(uu, ab) { \
          float2 dA = dpw[ab], dB = dpw[(ab) + 1]; \
          float xA = blo(uu) + dA.x, xB = bhi(uu) + dB.x; \
          float eA = __expf(2.f * xA), eB = __expf(2.f * xB); \
          acc += dA.y * (1.f - 2.f / (eA + 1.f)); \
          acc += dB.y * (1.f - 2.f / (eB + 1.f)); }
          SCP(v.x, aj) SCP(v.y, aj + 2) SCP(v.z, aj + 4) SCP(v.w, aj + 6)
#undef SCP
        }
      }
      spart[tid] = acc;
    }
    __syncthreads();

    // ---- softmax over s (196) ----
    float sc = -1e30f, ee = 0.f;
    if (tid < 256) sc = (tid < 196) ? (spart[tid] + spart[tid + 256]) : -1e30f;
    float mm = sc;
#pragma unroll
    for (int off = 32; off >= 1; off >>= 1) mm = fmaxf(mm, __shfl_xor(mm, off));
    if (tid < 256 && lane == 0) wred[wv] = mm;
    __syncthreads();
    float mx = fmaxf(fmaxf(wred[0], wred[1]), fmaxf(wred[2], wred[3]));
    if (tid < 256){
      ee = (tid < 196) ? __expf(sc - mx) : 0.f;
      sw[tid] = ee;
    }
    float ss = ee;
#pragma unroll
    for (int off = 32; off >= 1; off >>= 1) ss += __shfl_xor(ss, off);
    if (tid < 256 && lane == 0) wred[8 + wv] = ss;
    __syncthreads();
    float inv = 1.f / (wred[8] + wred[9] + wred[10] + wred[11]);

    // ---- context[e] = inv * sum_s sw[s]*enc_out[b,s,e] ----
    {
      int e2 = tid & 255, sh2 = tid >> 8;
      const unsigned int* src = eo2 + ((long)b * 196 + sh2 * 98) * 256 + e2;
      float a0 = 0.f, a1 = 0.f;
#pragma unroll 2
      for (int s2 = 0; s2 < 98; ++s2){
        unsigned int v = src[(long)s2 * 256];
        float w = sw[sh2 * 98 + s2];
        a0 += w * blo(v); a1 += w * bhi(v);
      }
      *(float2*)&spart[(sh2 << 9) | (e2 << 1)] = make_float2(a0, a1);
    }
    __syncthreads();
    sh_cb[tid] = f2b((spart[tid] + spart[tid + 512]) * inv);
    __syncthreads();

    // ---- giq = [Wih2 @ ctx | Whh @ h] via M=1 MFMA, frag-order weights ----
    // waves 0-3: gi (A=ctx), waves 4-7: gh (A=h). 24 n-tiles per wave.
    {
      const unsigned short* asrc = (wv < 4) ? sh_cb : sh_hb;
      uint4 af[16];
#pragma unroll
      for (int kit = 0; kit < 16; ++kit){
        uint4 av = *(const uint4*)&asrc[(kit << 5) + (quad << 3)];
        if (lrow) av = make_uint4(0, 0, 0, 0);
        af[kit] = av;
      }
      const unsigned short* wsrc = (wv < 4) ? Wihf : Whhf;
      int tbase = (wv & 3) * 24;
      int obase = (wv < 4) ? 0 : 1536;
      for (int i = 0; i < 24; ++i){
        int tl = tbase + i;
        const unsigned short* wb = wsrc + ((long)tl << 13) + (size_t)lane * 8;
        f32x4 a4 = {0.f, 0.f, 0.f, 0.f};
#pragma unroll
        for (int kit = 0; kit < 16; ++kit){
          bf16x8 bfrag = *(const bf16x8*)(wb + (kit << 9));
          bf16x8 afr; *(uint4*)&afr = af[kit];
          a4 = __builtin_amdgcn_mfma_f32_16x16x32_bf16(afr, bfrag, a4, 0, 0, 0);
        }
        if (lane < 16) giq_lds[obase + tl * 16 + lane] = a4[0];
      }
    }
    __syncthreads();   // giq ready for next step's gates; LDS reuse safe
  }
}

// ---------------------------------------------------------------------------
extern "C" void kernel_launch(void* const* d_in, const int* in_sizes, int n_in,
                              void* d_out, int out_size, void* d_ws, size_t ws_size,
                              hipStream_t stream)
{
  (void)in_sizes; (void)n_in; (void)out_size; (void)ws_size;
  const float* encoder_out = (const float*)d_in[0];
  const float* pooled      = (const float*)d_in[1];
  const int*   targets     = (const int*)d_in[2];
  const float* embedding   = (const float*)d_in[3];
  const float* W_enc  = (const float*)d_in[4];
  const float* b_enc  = (const float*)d_in[5];
  const float* W_dec  = (const float*)d_in[6];
  const float* b_dec  = (const float*)d_in[7];
  const float* W_score= (const float*)d_in[8];
  const float* W_ih   = (const float*)d_in[10];
  const float* W_hh   = (const float*)d_in[11];
  const float* b_ih   = (const float*)d_in[12];
  const float* b_hh   = (const float*)d_in[13];
  const float* W_out  = (const float*)d_in[14];
  const float* b_out  = (const float*)d_in[15];
  const float* W_init = (const float*)d_in[16];
  const float* b_init = (const float*)d_in[17];
  float* out = (float*)d_out;

  char* w = (char*)d_ws;
  unsigned short* eo_b16  = (unsigned short*)w; w += 12845056;  // 64*196*512 bf16
  float* gi_emb           = (float*)w;          w += 12189696;  // 31*64*1536 f32
  float* h_all            = (float*)w;          w += 131072;    // 64*512 f32 (t=0 only)
  unsigned short* h_b16   = (unsigned short*)w; w += 2097152;   // 32*64*512 bf16
  unsigned short* emb_b16 = (unsigned short*)w; w += 2031616;   // 1984*512 bf16
  unsigned short* Wout_b  = (unsigned short*)w; w += 32768000;
  unsigned short* Wih_b   = (unsigned short*)w; w += 3145728;
  unsigned short* WdecT_b = (unsigned short*)w; w += 262144;    // 512x256 bf16 k-major
  unsigned short* Winit_b = (unsigned short*)w; w += 524288;
  unsigned short* Wenc_b  = (unsigned short*)w; w += 262144;
  unsigned short* Wihf_b  = (unsigned short*)w; w += 1572864;   // frag-order Wih[:,512:]
  unsigned short* Whhf_b  = (unsigned short*)w; w += 1572864;   // frag-order Whh
  unsigned short* ep_b16  = (unsigned short*)w; w += 6422528;   // 64*196*256 bf16

  auto conv = [&](const float* s, unsigned short* d, int n){
    conv_k<<<dim3((n / 4 + 255) / 256), dim3(256), 0, stream>>>(s, d, n);
  };
  conv(W_out,  Wout_b,  32000 * 512);
  conv(W_ih,   Wih_b,   1536 * 1024);
  conv(W_init, Winit_b, 512 * 512);
  conv(W_enc,  Wenc_b,  256 * 512);
  conv(encoder_out, eo_b16, 64 * 196 * 512);
  wdect_k<<<dim3(512), dim3(256), 0, stream>>>(W_dec, WdecT_b);
  wfrag_k<<<dim3(3072), dim3(256), 0, stream>>>(W_ih, 1024, 512, Wihf_b);
  wfrag_k<<<dim3(3072), dim3(256), 0, stream>>>(W_hh, 512, 0, Whhf_b);
  embed_k<<<dim3((1984 * 512) / 256), dim3(256), 0, stream>>>(targets, embedding, emb_b16, 1984 * 512);

  // h0 = tanh(pooled @ W_init^T + b_init)
  gemm_bt<EPI_TANH, true><<<dim3(1, 2), 256, 0, stream>>>(
      pooled, 512, Winit_b, 512, b_init, h_all, h_b16, 512, 512, 0, nullptr, nullptr, 0, 0);
  // enc_proj (bf16 direct) = encoder_out @ W_enc^T + b_enc  (M=12544)
  gemm_bt<EPI_B16, true><<<dim3(196, 1), 256, 0, stream>>>(
      encoder_out, 512, Wenc_b, 512, b_enc, nullptr, ep_b16, 256, 512, 0, nullptr, nullptr, 0, 0);
  // gi_emb = embedded @ W_ih[:, :512]^T + b_ih  (M=1984)
  gemm_bt<EPI_PLAIN, false><<<dim3(31, 6), 256, 0, stream>>>(
      emb_b16, 512, Wih_b, 1024, b_ih, gi_emb, nullptr, 1536, 512, 0, nullptr, nullptr, 0, 0);

  // the entire 31-step recurrence: one persistent kernel, no grid syncs
  loop_k<<<dim3(64), dim3(512), 0, stream>>>(
      (const uint4*)ep_b16, (const unsigned int*)eo_b16, W_score, b_dec, b_hh,
      gi_emb, h_all, h_b16, (const uint2*)WdecT_b, Wihf_b, Whhf_b);

  // logits: (1984 x 32000 x 512), A = h_1..h_31, scatter to (b,t,v)
  gemm_bt<EPI_OUT, false><<<dim3(31, 125), 256, 0, stream>>>(
      h_b16 + 64 * 512, 512, Wout_b, 512, b_out, out, nullptr, 0, 512,
      0, nullptr, nullptr, 0, 0);
}

// Round 3
// 1998.073 us; speedup vs baseline: 2.9125x; 2.9125x over previous
//
#include <hip/hip_runtime.h>

using bf16x8 = __attribute__((ext_vector_type(8))) short;
using f32x4  = __attribute__((ext_vector_type(4))) float;

__device__ inline float bf2f(unsigned short h){
  union { unsigned int u; float f; } v; v.u = ((unsigned int)h) << 16; return v.f;
}
__device__ inline unsigned short f2b(float x){
  union { float f; unsigned int u; } v; v.f = x;
  unsigned int r = (v.u + 0x7FFFu + ((v.u >> 16) & 1u)) >> 16;
  return (unsigned short)r;
}
__device__ inline float blo(unsigned int u){ union{unsigned int v; float f;} t; t.v = u << 16; return t.f; }
__device__ inline float bhi(unsigned int u){ union{unsigned int v; float f;} t; t.v = u & 0xffff0000u; return t.f; }

// ---------------------------------------------------------------------------
// fp32 -> bf16 bulk convert (n multiple of 4)
__global__ void conv_k(const float* __restrict__ s, unsigned short* __restrict__ d, int n){
  int i = (blockIdx.x * 256 + threadIdx.x) * 4;
  if (i >= n) return;
  float4 v = *(const float4*)(s + i);
  unsigned int p0 = (unsigned int)f2b(v.x) | ((unsigned int)f2b(v.y) << 16);
  unsigned int p1 = (unsigned int)f2b(v.z) | ((unsigned int)f2b(v.w) << 16);
  *(uint2*)(d + i) = make_uint2(p0, p1);
}

// W_dec (256x512 f32) -> WdecT (512x256 bf16, k-major). Coalesced writes.
__global__ void wdect_k(const float* __restrict__ Wd, unsigned short* __restrict__ o){
  int idx = blockIdx.x * 256 + threadIdx.x;   // idx = k*256 + a
  int k = idx >> 8, a = idx & 255;
  o[idx] = f2b(Wd[a * 512 + k]);
}

// Reorder an f32 weight slice (row-major, ld, col offset koff, 1536x512)
// into MFMA-16x16x32 B-fragment order, bf16 (1 KB contiguous per (tile,kit)).
__global__ void wfrag_k(const float* __restrict__ src, int ld, int koff,
                        unsigned short* __restrict__ dst){
  int d = blockIdx.x * 256 + threadIdx.x;      // 1536*512 elements
  int j = d & 7, lane = (d >> 3) & 63, kit = (d >> 9) & 15, nt = d >> 13;
  int n = nt * 16 + (lane & 15);
  int k = kit * 32 + ((lane >> 4) << 3) + j;
  dst[d] = f2b(src[(long)n * ld + koff + k]);
}

// embedding gather (pad_idx=2 -> 0), rows m = t*64+b, bf16 out
__global__ void embed_k(const int* __restrict__ tgt, const float* __restrict__ emb,
                        unsigned short* __restrict__ out, int n){
  int idx = blockIdx.x * 256 + threadIdx.x;
  if (idx >= n) return;
  int d = idx & 511, m = idx >> 9, t = m >> 6, b = m & 63;
  int tok = tgt[b * 32 + t];
  float v = (tok == 2) ? 0.f : emb[(long)tok * 512 + d];
  out[idx] = f2b(v);
}

// ---------------------------------------------------------------------------
// Generic bf16 MFMA GEMM: C[m][n] = sum_k A[m][k]*B[n][k] (+bias[n])
#define EPI_PLAIN 0
#define EPI_TANH  1
#define EPI_OUT   2
#define EPI_B16   3

template<int EPI, bool AF32>
__global__ __launch_bounds__(256)
void gemm_bt(const void* __restrict__ Av, int lda,
             const unsigned short* __restrict__ Bp, int ldb,
             const float* __restrict__ bias,
             float* __restrict__ Cf, unsigned short* __restrict__ Cb, int ldc,
             int K,
             int n_split, const void* __restrict__ A2v,
             const unsigned short* __restrict__ B2p, int lda2, int ldb2)
{
  __shared__ __align__(16) unsigned short As[64][40];
  __shared__ __align__(16) unsigned short Bs[256][40];

  int bx = blockIdx.x, by = blockIdx.y;
  if (EPI == EPI_OUT){
    // bijective XCD swizzle: each XCD sweeps all m-blocks of a contiguous
    // n-range -> B-panel fetched once per XCD (L2-resident across m-sweep).
    unsigned nwg = gridDim.x * gridDim.y;
    unsigned orig = (unsigned)by * gridDim.x + bx;
    unsigned q = nwg >> 3, r = nwg & 7;
    unsigned xcd = orig & 7, pos = orig >> 3;
    unsigned swz = (xcd < r) ? (xcd * (q + 1) + pos)
                             : (r * (q + 1) + (xcd - r) * q + pos);
    bx = swz % gridDim.x; by = swz / gridDim.x;
  }
  int m0 = bx * 64;
  int n0 = by * 256;
  const void* Ap = Av; const unsigned short* Bq = Bp;
  int la = lda, lb = ldb, nB = n0;
  if (n_split > 0 && n0 >= n_split){ Ap = A2v; Bq = B2p; la = lda2; lb = ldb2; nB = n0 - n_split; }

  int tid  = threadIdx.x;
  int wave = tid >> 6, lane = tid & 63, quad = lane >> 4, lrow = lane & 15;

  f32x4 acc[4][4];
#pragma unroll
  for (int i = 0; i < 4; ++i)
#pragma unroll
    for (int j = 0; j < 4; ++j)
#pragma unroll
      for (int r = 0; r < 4; ++r) acc[i][j][r] = 0.f;

  int ar = tid >> 2, ac = (tid & 3) * 8;

  for (int k0 = 0; k0 < K; k0 += 32){
    if (AF32){
      const float* A32 = (const float*)Ap;
      const float4* src = (const float4*)(A32 + (long)(m0 + ar) * la + k0 + ac);
      float4 x0 = src[0], x1 = src[1];
      unsigned int p0 = (unsigned int)f2b(x0.x) | ((unsigned int)f2b(x0.y) << 16);
      unsigned int p1 = (unsigned int)f2b(x0.z) | ((unsigned int)f2b(x0.w) << 16);
      unsigned int p2 = (unsigned int)f2b(x1.x) | ((unsigned int)f2b(x1.y) << 16);
      unsigned int p3 = (unsigned int)f2b(x1.z) | ((unsigned int)f2b(x1.w) << 16);
      *(uint4*)&As[ar][ac] = make_uint4(p0, p1, p2, p3);
    } else {
      const unsigned short* A16 = (const unsigned short*)Ap;
      *(uint4*)&As[ar][ac] = *(const uint4*)(A16 + (long)(m0 + ar) * la + k0 + ac);
    }
#pragma unroll
    for (int c = 0; c < 4; ++c){
      int id = tid + c * 256; int br = id >> 2, bc = (id & 3) * 8;
      *(uint4*)&Bs[br][bc] = *(const uint4*)(Bq + (long)(nB + br) * lb + k0 + bc);
    }
    __syncthreads();

    bf16x8 af[4], bfr[4];
#pragma unroll
    for (int mf = 0; mf < 4; ++mf) af[mf]  = *(const bf16x8*)&As[mf * 16 + lrow][quad * 8];
#pragma unroll
    for (int nf = 0; nf < 4; ++nf) bfr[nf] = *(const bf16x8*)&Bs[wave * 64 + nf * 16 + lrow][quad * 8];
#pragma unroll
    for (int mf = 0; mf < 4; ++mf)
#pragma unroll
      for (int nf = 0; nf < 4; ++nf)
        acc[mf][nf] = __builtin_amdgcn_mfma_f32_16x16x32_bf16(af[mf], bfr[nf], acc[mf][nf], 0, 0, 0);
    __syncthreads();
  }

#pragma unroll
  for (int mf = 0; mf < 4; ++mf){
#pragma unroll
    for (int nf = 0; nf < 4; ++nf){
#pragma unroll
      for (int r = 0; r < 4; ++r){
        int m = m0 + mf * 16 + quad * 4 + r;
        int n = n0 + wave * 64 + nf * 16 + lrow;
        float v = acc[mf][nf][r];
        if (bias) v += bias[n];
        if (EPI == EPI_TANH){
          v = tanhf(v);
          Cf[(long)m * ldc + n] = v;
          Cb[(long)m * ldc + n] = f2b(v);
        } else if (EPI == EPI_OUT){
          Cf[(long)(m & 63) * (31 * 32000) + (long)(m >> 6) * 32000 + n] = v;
        } else if (EPI == EPI_B16){
          Cb[(long)m * ldc + n] = f2b(v);
        } else {
          Cf[(long)m * ldc + n] = v;
        }
      }
    }
  }
}

// ---------------------------------------------------------------------------
// Manual grid barrier. Safe because grid=64 blocks with ~111KB LDS -> 1
// block/CU, 64 <= 256 CUs -> all blocks co-resident. Counter state is
// memset to 0 before each launch; cnt self-resets every barrier.
__device__ inline void gridbar(unsigned* cnt, unsigned* gen, unsigned nblk){
  __syncthreads();
  if (threadIdx.x == 0){
    __threadfence();
    unsigned g = __hip_atomic_load(gen, __ATOMIC_RELAXED, __HIP_MEMORY_SCOPE_AGENT);
    unsigned old = __hip_atomic_fetch_add(cnt, 1u, __ATOMIC_ACQ_REL, __HIP_MEMORY_SCOPE_AGENT);
    if (old == nblk - 1u){
      __hip_atomic_store(cnt, 0u, __ATOMIC_RELAXED, __HIP_MEMORY_SCOPE_AGENT);
      __hip_atomic_fetch_add(gen, 1u, __ATOMIC_ACQ_REL, __HIP_MEMORY_SCOPE_AGENT);
    } else {
      while (__hip_atomic_load(gen, __ATOMIC_ACQUIRE, __HIP_MEMORY_SCOPE_AGENT) == g)
        __builtin_amdgcn_s_sleep(2);
    }
    __threadfence();
  }
  __syncthreads();
}

// ---------------------------------------------------------------------------
// Persistent decoder loop with grid barriers. 64 blocks x 512 threads.
// Block b owns batch b's attention (ep[b] persistent in LDS) AND a 48-column
// slice of the batched giq GEMM -> each weight byte is read once per step
// grid-wide (L2-resident), restoring the 64x cross-batch amortization.
__global__ __launch_bounds__(512)
void loop_k(const uint4* __restrict__ ep4,          // enc_proj bf16 [(b*196+s)*256+a]
            const unsigned int* __restrict__ eo2,   // enc_out bf16 pairs
            const float* __restrict__ W_score,
            const float* __restrict__ b_dec,
            const float* __restrict__ b_hh,
            const float* __restrict__ gi_emb,
            const float* __restrict__ h0_all,       // (64,512) f32
            unsigned short* __restrict__ h_b16,     // (32,64,512) bf16
            const uint2* __restrict__ WdecT4,       // bf16 [k][a] k-major
            const unsigned short* __restrict__ Wihf,// frag-order Wih[:,512:]
            const unsigned short* __restrict__ Whhf,// frag-order Whh
            unsigned short* __restrict__ ctx_b16,   // (64,512) bf16
            float* __restrict__ giq_g,              // (64,3072) f32
            unsigned* __restrict__ bar)
{
  __shared__ __align__(16) uint4 ep_s4[6272];       // 98 KB, swizzled
  __shared__ float sh_h[512];
  __shared__ float2 dpw[256];
  __shared__ float spart[2048];
  __shared__ float sw[256];
  __shared__ float wred[16];

  int b = blockIdx.x, tid = threadIdx.x;
  int lane = tid & 63, wv = tid >> 6, quad = lane >> 4, lrow = lane & 15;

  // loop-invariant preloads
  float wsc  = (tid < 256) ? W_score[tid] : 0.f;
  float bdec = (tid < 256) ? b_dec[tid] : 0.f;
  float bhh0 = b_hh[tid], bhh1 = b_hh[512 + tid], bhh2 = b_hh[1024 + tid];

  // stage enc_proj[b] once (chunk-XOR swizzle: conflict-free ds_read_b128)
  {
    const uint4* src = ep4 + (long)b * 6272;
    for (int c = tid; c < 6272; c += 512){
      int r = c >> 5, col = c & 31;
      ep_s4[(r << 5) | (col ^ (r & 7))] = src[c];
    }
  }

  // GEMM slice role (constant over t)
  int isgh = b >> 5;                        // 0: gi (A=ctx), 1: gh (A=h)
  int tl0 = (b & 31) * 3;                   // 3 n-tiles of 16 cols each
  const unsigned short* wsrc = isgh ? Whhf : Wihf;

  float h_prev = 0.f;
  unsigned* cnt = bar; unsigned* gen = bar + 64;

  for (int t = 0; t <= 31; ++t){
    // ---- GRU gates -> h_t (t=0: read h0) ----
    float hv;
    if (t > 0){
      int j = tid;
      long ge = ((long)(t - 1) * 64 + b) * 1536;
      long gq = (long)b * 3072;
      float gir = gi_emb[ge + j]        + giq_g[gq + j];
      float giz = gi_emb[ge + 512 + j]  + giq_g[gq + 512 + j];
      float gin = gi_emb[ge + 1024 + j] + giq_g[gq + 1024 + j];
      float ghr = giq_g[gq + 1536 + j] + bhh0;
      float ghz = giq_g[gq + 2048 + j] + bhh1;
      float ghn = giq_g[gq + 2560 + j] + bhh2;
      float rr = 1.f / (1.f + __expf(-(gir + ghr)));
      float zz = 1.f / (1.f + __expf(-(giz + ghz)));
      float nn = tanhf(gin + rr * ghn);
      hv = (1.f - zz) * nn + zz * h_prev;
      h_b16[((long)t * 64 + b) * 512 + j] = f2b(hv);
    } else {
      hv = h0_all[(long)b * 512 + tid];
    }
    h_prev = hv;
    if (t == 31) break;                 // uniform: h_31 written, done

    sh_h[tid] = hv;
    __syncthreads();

    // ---- dec_proj[a] = h . W_dec[a,:] + b_dec[a] (k-major GEMV, L2) ----
    {
      int a4 = tid & 63, kg = tid >> 6;
      const uint2* wp = WdecT4 + ((kg << 12) | a4);
      const float* hp = &sh_h[kg << 6];
      float ac0 = 0.f, ac1 = 0.f, ac2 = 0.f, ac3 = 0.f;
#pragma unroll 16
      for (int kk = 0; kk < 64; ++kk){
        uint2 wq = wp[kk << 6];
        float hk = hp[kk];
        ac0 += hk * blo(wq.x); ac1 += hk * bhi(wq.x);
        ac2 += hk * blo(wq.y); ac3 += hk * bhi(wq.y);
      }
      *(float4*)&spart[(kg << 8) | (a4 << 2)] = make_float4(ac0, ac1, ac2, ac3);
    }
    __syncthreads();
    if (tid < 256){
      float dp = bdec;
#pragma unroll
      for (int kg = 0; kg < 8; ++kg) dp += spart[(kg << 8) | tid];
      dpw[tid] = make_float2(dp, wsc);
    }
    __syncthreads();

    // ---- scores[s] = sum_a wsc[a]*tanh(ep[s][a]+dp[a]) ----
    {
      int s = tid & 255, half = tid >> 8;
      float acc = 0.f;
      if (s < 196){
        int rb = s << 5, sx = s & 7;
#pragma unroll 4
        for (int j = 0; j < 16; ++j){
          uint4 v = ep_s4[rb | (((half << 4) | j) ^ sx)];
          int aj = (half << 7) | (j << 3);
#define SCP(uu, ab) { \
          float2 dA = dpw[ab], dB = dpw[(ab) + 1]; \
          float xA = blo(uu) + dA.x, xB = bhi(uu) + dB.x; \
          float eA = __expf(2.f * xA), eB = __expf(2.f * xB); \
          acc += dA.y * (1.f - 2.f / (eA + 1.f)); \
          acc += dB.y * (1.f - 2.f / (eB + 1.f)); }
          SCP(v.x, aj) SCP(v.y, aj + 2) SCP(v.z, aj + 4) SCP(v.w, aj + 6)
#undef SCP
        }
      }
      spart[tid] = acc;
    }
    __syncthreads();

    // ---- softmax over s (196) ----
    float sc = -1e30f, ee = 0.f;
    if (tid < 256) sc = (tid < 196) ? (spart[tid] + spart[tid + 256]) : -1e30f;
    float mm = sc;
#pragma unroll
    for (int off = 32; off >= 1; off >>= 1) mm = fmaxf(mm, __shfl_xor(mm, off));
    if (tid < 256 && lane == 0) wred[wv] = mm;
    __syncthreads();
    float mx = fmaxf(fmaxf(wred[0], wred[1]), fmaxf(wred[2], wred[3]));
    if (tid < 256){
      ee = (tid < 196) ? __expf(sc - mx) : 0.f;
      sw[tid] = ee;
    }
    float ss = ee;
#pragma unroll
    for (int off = 32; off >= 1; off >>= 1) ss += __shfl_xor(ss, off);
    if (tid < 256 && lane == 0) wred[8 + wv] = ss;
    __syncthreads();
    float inv = 1.f / (wred[8] + wred[9] + wred[10] + wred[11]);

    // ---- context[e] = inv * sum_s sw[s]*enc_out[b,s,e] -> global bf16 ----
    {
      int e2 = tid & 255, sh2 = tid >> 8;
      const unsigned int* src = eo2 + ((long)b * 196 + sh2 * 98) * 256 + e2;
      float a0 = 0.f, a1 = 0.f;
#pragma unroll 2
      for (int s2 = 0; s2 < 98; ++s2){
        unsigned int v = src[(long)s2 * 256];
        float w = sw[sh2 * 98 + s2];
        a0 += w * blo(v); a1 += w * bhi(v);
      }
      *(float2*)&spart[(sh2 << 9) | (e2 << 1)] = make_float2(a0, a1);
    }
    __syncthreads();
    ctx_b16[(b << 9) | tid] = f2b((spart[tid] + spart[tid + 512]) * inv);

    gridbar(cnt, gen, 64);   // ctx_t + h_t visible everywhere

    // ---- batched giq GEMM, this block's 48-column slice (M=64, K=512) ----
    {
      const unsigned short* Asrc = isgh ? (h_b16 + (long)t * 64 * 512) : ctx_b16;
      for (int ti = wv; ti < 12; ti += 8){
        int mt = ti & 3, nt = ti >> 2;
        int tl = tl0 + nt;
        const unsigned short* wb = wsrc + ((long)tl << 13) + (size_t)lane * 8;
        const unsigned short* ab = Asrc + (size_t)(mt * 16 + lrow) * 512 + quad * 8;
        f32x4 a4 = {0.f, 0.f, 0.f, 0.f};
#pragma unroll
        for (int kit = 0; kit < 16; ++kit){
          bf16x8 bfrag = *(const bf16x8*)(wb + (kit << 9));
          bf16x8 afrag = *(const bf16x8*)(ab + (kit << 5));
          a4 = __builtin_amdgcn_mfma_f32_16x16x32_bf16(afrag, bfrag, a4, 0, 0, 0);
        }
        int col = isgh * 1536 + tl * 16 + lrow;
#pragma unroll
        for (int r = 0; r < 4; ++r)
          giq_g[(long)(mt * 16 + quad * 4 + r) * 3072 + col] = a4[r];
      }
    }

    gridbar(cnt, gen, 64);   // giq_t visible -> gates t+1
  }
}

// ---------------------------------------------------------------------------
extern "C" void kernel_launch(void* const* d_in, const int* in_sizes, int n_in,
                              void* d_out, int out_size, void* d_ws, size_t ws_size,
                              hipStream_t stream)
{
  (void)in_sizes; (void)n_in; (void)out_size; (void)ws_size;
  const float* encoder_out = (const float*)d_in[0];
  const float* pooled      = (const float*)d_in[1];
  const int*   targets     = (const int*)d_in[2];
  const float* embedding   = (const float*)d_in[3];
  const float* W_enc  = (const float*)d_in[4];
  const float* b_enc  = (const float*)d_in[5];
  const float* W_dec  = (const float*)d_in[6];
  const float* b_dec  = (const float*)d_in[7];
  const float* W_score= (const float*)d_in[8];
  const float* W_ih   = (const float*)d_in[10];
  const float* W_hh   = (const float*)d_in[11];
  const float* b_ih   = (const float*)d_in[12];
  const float* b_hh   = (const float*)d_in[13];
  const float* W_out  = (const float*)d_in[14];
  const float* b_out  = (const float*)d_in[15];
  const float* W_init = (const float*)d_in[16];
  const float* b_init = (const float*)d_in[17];
  float* out = (float*)d_out;

  char* w = (char*)d_ws;
  unsigned short* eo_b16  = (unsigned short*)w; w += 12845056;  // 64*196*512 bf16
  float* gi_emb           = (float*)w;          w += 12189696;  // 31*64*1536 f32
  float* h_all            = (float*)w;          w += 131072;    // 64*512 f32 (t=0)
  unsigned short* h_b16   = (unsigned short*)w; w += 2097152;   // 32*64*512 bf16
  unsigned short* emb_b16 = (unsigned short*)w; w += 2031616;   // 1984*512 bf16
  unsigned short* Wout_b  = (unsigned short*)w; w += 32768000;
  unsigned short* Wih_b   = (unsigned short*)w; w += 3145728;
  unsigned short* WdecT_b = (unsigned short*)w; w += 262144;    // 512x256 bf16 k-major
  unsigned short* Winit_b = (unsigned short*)w; w += 524288;
  unsigned short* Wenc_b  = (unsigned short*)w; w += 262144;
  unsigned short* Wihf_b  = (unsigned short*)w; w += 1572864;   // frag-order Wih[:,512:]
  unsigned short* Whhf_b  = (unsigned short*)w; w += 1572864;   // frag-order Whh
  unsigned short* ep_b16  = (unsigned short*)w; w += 6422528;   // 64*196*256 bf16
  unsigned short* ctx_b16 = (unsigned short*)w; w += 65536;     // 64*512 bf16
  float* giq_g            = (float*)w;          w += 786432;    // 64*3072 f32
  unsigned* bar           = (unsigned*)w;       w += 512;       // grid barrier state

  hipMemsetAsync(bar, 0, 512, stream);

  auto conv = [&](const float* s, unsigned short* d, int n){
    conv_k<<<dim3((n / 4 + 255) / 256), dim3(256), 0, stream>>>(s, d, n);
  };
  conv(W_out,  Wout_b,  32000 * 512);
  conv(W_ih,   Wih_b,   1536 * 1024);
  conv(W_init, Winit_b, 512 * 512);
  conv(W_enc,  Wenc_b,  256 * 512);
  conv(encoder_out, eo_b16, 64 * 196 * 512);
  wdect_k<<<dim3(512), dim3(256), 0, stream>>>(W_dec, WdecT_b);
  wfrag_k<<<dim3(3072), dim3(256), 0, stream>>>(W_ih, 1024, 512, Wihf_b);
  wfrag_k<<<dim3(3072), dim3(256), 0, stream>>>(W_hh, 512, 0, Whhf_b);
  embed_k<<<dim3((1984 * 512) / 256), dim3(256), 0, stream>>>(targets, embedding, emb_b16, 1984 * 512);

  // h0 = tanh(pooled @ W_init^T + b_init)
  gemm_bt<EPI_TANH, true><<<dim3(1, 2), 256, 0, stream>>>(
      pooled, 512, Winit_b, 512, b_init, h_all, h_b16, 512, 512, 0, nullptr, nullptr, 0, 0);
  // enc_proj (bf16 direct) = encoder_out @ W_enc^T + b_enc  (M=12544)
  gemm_bt<EPI_B16, true><<<dim3(196, 1), 256, 0, stream>>>(
      encoder_out, 512, Wenc_b, 512, b_enc, nullptr, ep_b16, 256, 512, 0, nullptr, nullptr, 0, 0);
  // gi_emb = embedded @ W_ih[:, :512]^T + b_ih  (M=1984)
  gemm_bt<EPI_PLAIN, false><<<dim3(31, 6), 256, 0, stream>>>(
      emb_b16, 512, Wih_b, 1024, b_ih, gi_emb, nullptr, 1536, 512, 0, nullptr, nullptr, 0, 0);

  // the entire 31-step recurrence: one persistent kernel, barrier-synced
  loop_k<<<dim3(64), dim3(512), 0, stream>>>(
      (const uint4*)ep_b16, (const unsigned int*)eo_b16, W_score, b_dec, b_hh,
      gi_emb, h_all, h_b16, (const uint2*)WdecT_b, Wihf_b, Whhf_b,
      ctx_b16, giq_g, bar);

  // logits: (1984 x 32000 x 512), A = h_1..h_31, scatter to (b,t,v)
  gemm_bt<EPI_OUT, false><<<dim3(31, 125), 256, 0, stream>>>(
      h_b16 + 64 * 512, 512, Wout_b, 512, b_out, out, nullptr, 0, 512,
      0, nullptr, nullptr, 0, 0);
}